// Round 2
// baseline (1062.249 us; speedup 1.0000x reference)
//
#include <hip/hip_runtime.h>
#include <math.h>

#define BATCH 2
#define SEQ 2048
#define DMODEL 1024
#define NHEAD 16
#define DHEAD 64
#define MTOT (BATCH*SEQ)   // 4096

// ------------------------------------------------------------------
// GEMM: out = X[M,1024] @ W[1024,1024]^T + bias    (torch Linear)
// 64x64 tile, BK=16, 256 threads, 4x4 micro-tile per thread.
// SPLIT=1: scatter output to [B,H,S,DK] head-split layout.
// SPLIT=0: plain [M,N] row-major.
// ------------------------------------------------------------------
template<int SPLIT>
__global__ __launch_bounds__(256)
void gemm_bias_kernel(const float* __restrict__ X, const float* __restrict__ W,
                      const float* __restrict__ bias, float* __restrict__ out)
{
    constexpr int K = DMODEL;
    __shared__ float As[16][68];   // [k][m], padded
    __shared__ float Bs[16][68];   // [k][n]

    const int t  = threadIdx.x;
    const int rm = t & 15;         // row group  (4 rows each)
    const int cn = t >> 4;         // col group  (4 cols each)
    const int m0 = blockIdx.y * 64;
    const int n0 = blockIdx.x * 64;

    const int lrow = t >> 2;       // 0..63
    const int lk4  = (t & 3) * 4;  // 0,4,8,12

    float acc[4][4] = {};

    for (int k0 = 0; k0 < K; k0 += 16) {
        // stage X tile 64x16 -> As[k][m] (transposed), W tile -> Bs[k][n]
        {
            const float4 x4 = *reinterpret_cast<const float4*>(
                &X[(size_t)(m0 + lrow) * K + k0 + lk4]);
            As[lk4 + 0][lrow] = x4.x; As[lk4 + 1][lrow] = x4.y;
            As[lk4 + 2][lrow] = x4.z; As[lk4 + 3][lrow] = x4.w;
            const float4 w4 = *reinterpret_cast<const float4*>(
                &W[(size_t)(n0 + lrow) * K + k0 + lk4]);
            Bs[lk4 + 0][lrow] = w4.x; Bs[lk4 + 1][lrow] = w4.y;
            Bs[lk4 + 2][lrow] = w4.z; Bs[lk4 + 3][lrow] = w4.w;
        }
        __syncthreads();
        #pragma unroll
        for (int kk = 0; kk < 16; ++kk) {
            const float4 a = *reinterpret_cast<const float4*>(&As[kk][rm * 4]);
            const float4 b = *reinterpret_cast<const float4*>(&Bs[kk][cn * 4]);
            const float av[4] = {a.x, a.y, a.z, a.w};
            const float bv[4] = {b.x, b.y, b.z, b.w};
            #pragma unroll
            for (int i = 0; i < 4; ++i)
                #pragma unroll
                for (int j = 0; j < 4; ++j)
                    acc[i][j] += av[i] * bv[j];
        }
        __syncthreads();
    }

    #pragma unroll
    for (int i = 0; i < 4; ++i) {
        const int m = m0 + rm * 4 + i;
        const int b = m >> 11;     // m / 2048
        const int s = m & 2047;
        #pragma unroll
        for (int j = 0; j < 4; ++j) {
            const int n = n0 + cn * 4 + j;
            const float c = acc[i][j] + bias[n];
            if (SPLIT) {
                const int h = n >> 6, dk = n & 63;
                out[(((size_t)(b * NHEAD + h)) * SEQ + s) * DHEAD + dk] = c;
            } else {
                out[(size_t)m * DMODEL + n] = c;
            }
        }
    }
}

// ------------------------------------------------------------------
// Causal flash attention: block = (b,h, 64-row q tile), 256 threads.
// Q,K,V in [B,H,S,DK]; writes ctx in [B,S,D] (head-interleaved).
// ------------------------------------------------------------------
__global__ __launch_bounds__(256)
void attn_kernel(const float* __restrict__ Q, const float* __restrict__ K,
                 const float* __restrict__ V, float* __restrict__ ctx)
{
    __shared__ float Qt[64][68];    // Qt[d][i], pre-scaled by 1/8
    __shared__ float Kt[64][68];    // Kt[d][j]
    __shared__ float Vs[64][68];    // Vs[j][d]
    __shared__ float Pst[64][68];   // Pst[j][i]
    __shared__ float rowm[64], rowl[64], rowscale[64];

    const int t  = threadIdx.x;
    const int rm = t & 15;          // i group (4 rows)
    const int cn = t >> 4;          // j / d group (4 cols)
    const int bh = blockIdx.x >> 5; // 0..31
    const int qt = blockIdx.x & 31; // q tile index
    const int q0 = qt * 64;

    const float* Qb = Q + (size_t)bh * SEQ * DHEAD;
    const float* Kb = K + (size_t)bh * SEQ * DHEAD;
    const float* Vb = V + (size_t)bh * SEQ * DHEAD;

    const int lrow = t >> 2;        // 0..63
    const int ld4  = (t & 3) * 4;   // 0,4,8,12 (+ c*16 below covers all 64)

    // stage Q tile transposed (64x64 = 4 float4 per thread), pre-scaled by 1/8
    #pragma unroll
    for (int c = 0; c < 4; ++c) {
        const int col = c * 16 + ld4;
        const float4 q4 = *reinterpret_cast<const float4*>(
            &Qb[(size_t)(q0 + lrow) * DHEAD + col]);
        Qt[col + 0][lrow] = q4.x * 0.125f;
        Qt[col + 1][lrow] = q4.y * 0.125f;
        Qt[col + 2][lrow] = q4.z * 0.125f;
        Qt[col + 3][lrow] = q4.w * 0.125f;
    }
    if (t < 64) { rowm[t] = -INFINITY; rowl[t] = 0.0f; }

    float O[4][4] = {};
    __syncthreads();

    for (int kt = 0; kt <= qt; ++kt) {
        const int k0 = kt * 64;
        // stage K tile transposed, V tile row-major (4 float4 each per thread)
        #pragma unroll
        for (int c = 0; c < 4; ++c) {
            const int col = c * 16 + ld4;
            const float4 k4 = *reinterpret_cast<const float4*>(
                &Kb[(size_t)(k0 + lrow) * DHEAD + col]);
            Kt[col + 0][lrow] = k4.x; Kt[col + 1][lrow] = k4.y;
            Kt[col + 2][lrow] = k4.z; Kt[col + 3][lrow] = k4.w;
            const float4 v4 = *reinterpret_cast<const float4*>(
                &Vb[(size_t)(k0 + lrow) * DHEAD + col]);
            *reinterpret_cast<float4*>(&Vs[lrow][col]) = v4;
        }
        __syncthreads();

        // scores: 4x4 per thread, rows i=rm*4.., cols j=cn*4..
        float sacc[4][4] = {};
        #pragma unroll 8
        for (int d = 0; d < 64; ++d) {
            const float4 q4 = *reinterpret_cast<const float4*>(&Qt[d][rm * 4]);
            const float4 k4 = *reinterpret_cast<const float4*>(&Kt[d][cn * 4]);
            const float qv[4] = {q4.x, q4.y, q4.z, q4.w};
            const float kv[4] = {k4.x, k4.y, k4.z, k4.w};
            #pragma unroll
            for (int ii = 0; ii < 4; ++ii)
                #pragma unroll
                for (int jj = 0; jj < 4; ++jj)
                    sacc[ii][jj] += qv[ii] * kv[jj];
        }
        const bool diag = (kt == qt);
        #pragma unroll
        for (int jj = 0; jj < 4; ++jj) {
            const int j = cn * 4 + jj;
            #pragma unroll
            for (int ii = 0; ii < 4; ++ii) {
                const int i = rm * 4 + ii;
                float sc = sacc[ii][jj];
                if (diag && j > i) sc = -INFINITY;
                Pst[j][i] = sc;
            }
        }
        __syncthreads();

        // online softmax, one lane per row; column reads of Pst are conflict-free
        if (t < 64) {
            const int r = t;
            const float mold = rowm[r];
            float tmax = -INFINITY;
            for (int j = 0; j < 64; ++j) tmax = fmaxf(tmax, Pst[j][r]);
            const float mnew = fmaxf(mold, tmax);
            const float sc = __expf(mold - mnew);   // first tile: exp(-inf)=0
            float ssum = 0.0f;
            for (int j = 0; j < 64; ++j) {
                const float p = __expf(Pst[j][r] - mnew);
                Pst[j][r] = p;
                ssum += p;
            }
            rowm[r] = mnew;
            rowl[r] = rowl[r] * sc + ssum;
            rowscale[r] = sc;
        }
        __syncthreads();

        // rescale accumulators, then PV
        float rs[4];
        #pragma unroll
        for (int ii = 0; ii < 4; ++ii) rs[ii] = rowscale[rm * 4 + ii];
        #pragma unroll
        for (int ii = 0; ii < 4; ++ii)
            #pragma unroll
            for (int dd = 0; dd < 4; ++dd)
                O[ii][dd] *= rs[ii];

        #pragma unroll 8
        for (int j = 0; j < 64; ++j) {
            const float4 p4 = *reinterpret_cast<const float4*>(&Pst[j][rm * 4]);
            const float4 v4 = *reinterpret_cast<const float4*>(&Vs[j][cn * 4]);
            const float pv[4] = {p4.x, p4.y, p4.z, p4.w};
            const float vv[4] = {v4.x, v4.y, v4.z, v4.w};
            #pragma unroll
            for (int ii = 0; ii < 4; ++ii)
                #pragma unroll
                for (int dd = 0; dd < 4; ++dd)
                    O[ii][dd] += pv[ii] * vv[dd];
        }
        __syncthreads();   // protect K/V/P tiles before next iteration
    }

    // epilogue: normalize and write ctx[B,S,D] with head interleave
    const int b = bh >> 4;
    const int h = bh & 15;
    #pragma unroll
    for (int ii = 0; ii < 4; ++ii) {
        const int i = rm * 4 + ii;
        const float inv = 1.0f / rowl[i];
        float4 o4;
        o4.x = O[ii][0] * inv; o4.y = O[ii][1] * inv;
        o4.z = O[ii][2] * inv; o4.w = O[ii][3] * inv;
        *reinterpret_cast<float4*>(
            &ctx[((size_t)(b * SEQ + q0 + i)) * DMODEL + h * DHEAD + cn * 4]) = o4;
    }
}

// ------------------------------------------------------------------
extern "C" void kernel_launch(void* const* d_in, const int* in_sizes, int n_in,
                              void* d_out, int out_size, void* d_ws, size_t ws_size,
                              hipStream_t stream)
{
    const float* query = (const float*)d_in[0];
    const float* key   = (const float*)d_in[1];
    const float* value = (const float*)d_in[2];
    // d_in[3] = mask: fixed causal tril by construction — implemented directly
    const float* Wq = (const float*)d_in[4];
    const float* bq = (const float*)d_in[5];
    const float* Wk = (const float*)d_in[6];
    const float* bk = (const float*)d_in[7];
    const float* Wv = (const float*)d_in[8];
    const float* bv = (const float*)d_in[9];
    const float* Wo = (const float*)d_in[10];
    const float* bo = (const float*)d_in[11];
    float* out = (float*)d_out;

    float* ws  = (float*)d_ws;
    const size_t planesz = (size_t)MTOT * DMODEL;   // 4M floats = 16MB
    float* q   = ws;
    float* k   = ws + planesz;
    float* v   = ws + 2 * planesz;
    float* ctx = ws + 3 * planesz;

    const dim3 gg(DMODEL / 64, MTOT / 64);
    const dim3 bb(256);
    gemm_bias_kernel<1><<<gg, bb, 0, stream>>>(query, Wq, bq, q);
    gemm_bias_kernel<1><<<gg, bb, 0, stream>>>(key,   Wk, bk, k);
    gemm_bias_kernel<1><<<gg, bb, 0, stream>>>(value, Wv, bv, v);
    attn_kernel<<<dim3(BATCH * NHEAD * (SEQ / 64)), bb, 0, stream>>>(q, k, v, ctx);
    gemm_bias_kernel<0><<<gg, bb, 0, stream>>>(ctx, Wo, bo, out);
}

// Round 3
// 608.733 us; speedup vs baseline: 1.7450x; 1.7450x over previous
//
#include <hip/hip_runtime.h>
#include <hip/hip_bf16.h>
#include <math.h>

#define BATCH 2
#define SEQ 2048
#define DMODEL 1024
#define NHEAD 16
#define DHEAD 64
#define MTOT (BATCH*SEQ)   // 4096

typedef __attribute__((ext_vector_type(8))) short bf16x8;
typedef __attribute__((ext_vector_type(4))) float f32x4;

static __device__ inline short f2bs(float x) {
    __hip_bfloat16 b = __float2bfloat16(x);
    return *reinterpret_cast<short*>(&b);
}

// ------------------------------------------------------------------
// GEMM: out = X[M,1024] @ W[1024,1024]^T + bias  (fp32 VALU core)
// SPLIT=1: write bf16, scaled, scattered to [B,H,S,DK]
// SPLIT=0: write fp32 [M,N] row-major
// ------------------------------------------------------------------
template<int SPLIT>
__global__ __launch_bounds__(256)
void gemm_bias_kernel(const float* __restrict__ X, const float* __restrict__ W,
                      const float* __restrict__ bias, void* __restrict__ outp,
                      float scale)
{
    constexpr int K = DMODEL;
    __shared__ float As[16][68];   // [k][m]
    __shared__ float Bs[16][68];   // [k][n]

    const int t  = threadIdx.x;
    const int rm = t & 15;
    const int cn = t >> 4;
    const int m0 = blockIdx.y * 64;
    const int n0 = blockIdx.x * 64;

    const int lrow = t >> 2;
    const int lk4  = (t & 3) * 4;

    float acc[4][4] = {};

    for (int k0 = 0; k0 < K; k0 += 16) {
        {
            const float4 x4 = *reinterpret_cast<const float4*>(
                &X[(size_t)(m0 + lrow) * K + k0 + lk4]);
            As[lk4 + 0][lrow] = x4.x; As[lk4 + 1][lrow] = x4.y;
            As[lk4 + 2][lrow] = x4.z; As[lk4 + 3][lrow] = x4.w;
            const float4 w4 = *reinterpret_cast<const float4*>(
                &W[(size_t)(n0 + lrow) * K + k0 + lk4]);
            Bs[lk4 + 0][lrow] = w4.x; Bs[lk4 + 1][lrow] = w4.y;
            Bs[lk4 + 2][lrow] = w4.z; Bs[lk4 + 3][lrow] = w4.w;
        }
        __syncthreads();
        #pragma unroll
        for (int kk = 0; kk < 16; ++kk) {
            const float4 a = *reinterpret_cast<const float4*>(&As[kk][rm * 4]);
            const float4 b = *reinterpret_cast<const float4*>(&Bs[kk][cn * 4]);
            const float av[4] = {a.x, a.y, a.z, a.w};
            const float bv[4] = {b.x, b.y, b.z, b.w};
            #pragma unroll
            for (int i = 0; i < 4; ++i)
                #pragma unroll
                for (int j = 0; j < 4; ++j)
                    acc[i][j] += av[i] * bv[j];
        }
        __syncthreads();
    }

    #pragma unroll
    for (int i = 0; i < 4; ++i) {
        const int m = m0 + rm * 4 + i;
        const int b = m >> 11;
        const int s = m & 2047;
        #pragma unroll
        for (int j = 0; j < 4; ++j) {
            const int n = n0 + cn * 4 + j;
            const float c = (acc[i][j] + bias[n]) * scale;
            if (SPLIT) {
                const int h = n >> 6, dk = n & 63;
                ((__hip_bfloat16*)outp)[(((size_t)(b * NHEAD + h)) * SEQ + s) * DHEAD + dk]
                    = __float2bfloat16(c);
            } else {
                ((float*)outp)[(size_t)m * DMODEL + n] = c;
            }
        }
    }
}

// ------------------------------------------------------------------
// MFMA bf16 causal flash attention.
// Block: 256 thr = 4 waves; 64 q-rows/block (16 per wave); KV tile 64.
// Q,K,V bf16 [B,H,S,DK]; ctx fp32 [B,S,D].
// MFMA 16x16x32 layouts: A: lane holds A[l&15][8*(l>>4)+j];
//                        B: lane holds B[8*(l>>4)+j][l&15];
//                        C/D: row=(l>>4)*4+reg, col=l&15.
// ------------------------------------------------------------------
__global__ __launch_bounds__(256)
void attn_mfma_kernel(const __hip_bfloat16* __restrict__ Q,
                      const __hip_bfloat16* __restrict__ K,
                      const __hip_bfloat16* __restrict__ V,
                      float* __restrict__ ctx)
{
    __shared__ short Ks[64 * 64];      // K tile [kpos][d], XOR-swizzled rows (128B)
    __shared__ short Vts[64 * 64];     // V^T tile [d][kpos], XOR-swizzled rows
    __shared__ short Ps[4 * 16 * 72];  // per-wave P [q_local][kpos], stride 72

    const int t    = threadIdx.x;
    const int lane = t & 63;
    const int w    = t >> 6;       // wave 0..3
    const int m    = lane & 15;
    const int g    = lane >> 4;    // 0..3

    const int bh = blockIdx.x >> 5;   // 0..31
    const int qt = blockIdx.x & 31;
    const int q0 = qt * 64;

    const __hip_bfloat16* Qb = Q + (size_t)bh * SEQ * DHEAD;
    const __hip_bfloat16* Kb = K + (size_t)bh * SEQ * DHEAD;
    const __hip_bfloat16* Vb = V + (size_t)bh * SEQ * DHEAD;

    // Q A-fragments (2 K-chunks of 32), resident in registers all kernel
    bf16x8 qfrag[2];
    #pragma unroll
    for (int c = 0; c < 2; ++c)
        qfrag[c] = *reinterpret_cast<const bf16x8*>(
            &Qb[(size_t)(q0 + 16 * w + m) * DHEAD + c * 32 + 8 * g]);

    f32x4 o[4] = {};                 // O accum: 4 d-tiles x (4 rows/lane)
    float mrow[4], lrow[4];
    #pragma unroll
    for (int r = 0; r < 4; ++r) { mrow[r] = -INFINITY; lrow[r] = 0.0f; }

    short* Pw = Ps + w * 16 * 72;

    for (int kt = 0; kt <= qt; ++kt) {
        const int k0 = kt * 64;

        // ---- stage K tile (row-major, swizzled) ----
        {
            const int row = t >> 2;
            #pragma unroll
            for (int cc = 0; cc < 2; ++cc) {
                const int ch = (t & 3) + cc * 4;   // 16B chunk 0..7
                const bf16x8 kv = *reinterpret_cast<const bf16x8*>(
                    &Kb[(size_t)(k0 + row) * DHEAD + ch * 8]);
                *reinterpret_cast<bf16x8*>((char*)Ks +
                    (((row * 128) + ch * 16) ^ ((row & 7) << 4))) = kv;
            }
            // ---- stage V^T tile (transpose via scalar writes, swizzled) ----
            const int vk = t & 63;
            #pragma unroll
            for (int it = 0; it < 2; ++it) {
                const int d0 = (t >> 6) * 16 + it * 8;
                const bf16x8 vv = *reinterpret_cast<const bf16x8*>(
                    &Vb[(size_t)(k0 + vk) * DHEAD + d0]);
                #pragma unroll
                for (int j = 0; j < 8; ++j) {
                    const int d = d0 + j;
                    *reinterpret_cast<short*>((char*)Vts +
                        (((d * 128) + vk * 2) ^ ((d & 7) << 4))) = vv[j];
                }
            }
        }
        __syncthreads();

        // ---- S = Q K^T : 4 col-tiles x 2 k-chunks ----
        f32x4 s[4] = {};
        #pragma unroll
        for (int ct = 0; ct < 4; ++ct) {
            const int krow = ct * 16 + m;
            #pragma unroll
            for (int c = 0; c < 2; ++c) {
                const bf16x8 kf = *reinterpret_cast<const bf16x8*>((char*)Ks +
                    (((krow * 128) + c * 64 + 16 * g) ^ ((krow & 7) << 4)));
                s[ct] = __builtin_amdgcn_mfma_f32_16x16x32_bf16(
                    qfrag[c], kf, s[ct], 0, 0, 0);
            }
        }

        // ---- causal mask on diagonal tile ----
        if (kt == qt) {
            #pragma unroll
            for (int ct = 0; ct < 4; ++ct) {
                const int kp = ct * 16 + m;
                #pragma unroll
                for (int r = 0; r < 4; ++r) {
                    const int qr = 16 * w + 4 * g + r;
                    if (kp > qr) s[ct][r] = -INFINITY;
                }
            }
        }

        // ---- online softmax (row-reduce across the 16-lane col dim) ----
        float pmax[4];
        #pragma unroll
        for (int r = 0; r < 4; ++r)
            pmax[r] = fmaxf(fmaxf(s[0][r], s[1][r]), fmaxf(s[2][r], s[3][r]));
        #pragma unroll
        for (int mk = 1; mk <= 8; mk <<= 1)
            #pragma unroll
            for (int r = 0; r < 4; ++r)
                pmax[r] = fmaxf(pmax[r], __shfl_xor(pmax[r], mk, 64));

        float scl[4];
        #pragma unroll
        for (int r = 0; r < 4; ++r) {
            const float mnew = fmaxf(mrow[r], pmax[r]);
            scl[r]  = __expf(mrow[r] - mnew);   // first tile: exp(-inf)=0
            mrow[r] = mnew;
        }
        #pragma unroll
        for (int ct = 0; ct < 4; ++ct)
            #pragma unroll
            for (int r = 0; r < 4; ++r)
                s[ct][r] = __expf(s[ct][r] - mrow[r]);

        float psum[4];
        #pragma unroll
        for (int r = 0; r < 4; ++r)
            psum[r] = (s[0][r] + s[1][r]) + (s[2][r] + s[3][r]);
        #pragma unroll
        for (int mk = 1; mk <= 8; mk <<= 1)
            #pragma unroll
            for (int r = 0; r < 4; ++r)
                psum[r] += __shfl_xor(psum[r], mk, 64);
        #pragma unroll
        for (int r = 0; r < 4; ++r)
            lrow[r] = lrow[r] * scl[r] + psum[r];

        // rescale O
        #pragma unroll
        for (int dt = 0; dt < 4; ++dt)
            #pragma unroll
            for (int r = 0; r < 4; ++r)
                o[dt][r] *= scl[r];

        // ---- write P (bf16) to per-wave LDS, [q_local][kpos] stride 72 ----
        #pragma unroll
        for (int ct = 0; ct < 4; ++ct)
            #pragma unroll
            for (int r = 0; r < 4; ++r)
                Pw[(4 * g + r) * 72 + ct * 16 + m] = f2bs(s[ct][r]);

        // ---- O += P V : A-frags from Pw, B-frags from Vts ----
        bf16x8 pf[2];
        #pragma unroll
        for (int c = 0; c < 2; ++c)
            pf[c] = *reinterpret_cast<const bf16x8*>(&Pw[m * 72 + c * 32 + 8 * g]);
        #pragma unroll
        for (int dt = 0; dt < 4; ++dt) {
            const int vrow = dt * 16 + m;
            #pragma unroll
            for (int c = 0; c < 2; ++c) {
                const bf16x8 vf = *reinterpret_cast<const bf16x8*>((char*)Vts +
                    (((vrow * 128) + c * 64 + 16 * g) ^ ((vrow & 7) << 4)));
                o[dt] = __builtin_amdgcn_mfma_f32_16x16x32_bf16(
                    pf[c], vf, o[dt], 0, 0, 0);
            }
        }
        __syncthreads();   // K/Vt consumed; safe to restage
    }

    // ---- epilogue: normalize, write ctx fp32 [B,S,D] head-interleaved ----
    const int b = bh >> 4;
    const int h = bh & 15;
    #pragma unroll
    for (int r = 0; r < 4; ++r) {
        const float inv = 1.0f / lrow[r];
        const int qrow = q0 + 16 * w + 4 * g + r;
        float* dst = &ctx[((size_t)(b * SEQ) + qrow) * DMODEL + h * DHEAD];
        #pragma unroll
        for (int dt = 0; dt < 4; ++dt)
            dst[dt * 16 + m] = o[dt][r] * inv;
    }
}

// ------------------------------------------------------------------
extern "C" void kernel_launch(void* const* d_in, const int* in_sizes, int n_in,
                              void* d_out, int out_size, void* d_ws, size_t ws_size,
                              hipStream_t stream)
{
    const float* query = (const float*)d_in[0];
    const float* key   = (const float*)d_in[1];
    const float* value = (const float*)d_in[2];
    // d_in[3] = mask: fixed causal tril — implemented directly
    const float* Wq = (const float*)d_in[4];
    const float* bq = (const float*)d_in[5];
    const float* Wk = (const float*)d_in[6];
    const float* bk = (const float*)d_in[7];
    const float* Wv = (const float*)d_in[8];
    const float* bv = (const float*)d_in[9];
    const float* Wo = (const float*)d_in[10];
    const float* bo = (const float*)d_in[11];
    float* out = (float*)d_out;

    // workspace: q,k,v bf16 (8MB each) then ctx f32 (16MB)
    char* ws = (char*)d_ws;
    __hip_bfloat16* qb = (__hip_bfloat16*)ws;
    __hip_bfloat16* kb = (__hip_bfloat16*)(ws + (size_t)MTOT * DMODEL * 2);
    __hip_bfloat16* vb = (__hip_bfloat16*)(ws + (size_t)MTOT * DMODEL * 4);
    float*          ctx = (float*)(ws + (size_t)MTOT * DMODEL * 8);

    const dim3 gg(DMODEL / 64, MTOT / 64);
    const dim3 bb(256);
    gemm_bias_kernel<1><<<gg, bb, 0, stream>>>(query, Wq, bq, qb, 0.125f);
    gemm_bias_kernel<1><<<gg, bb, 0, stream>>>(key,   Wk, bk, kb, 1.0f);
    gemm_bias_kernel<1><<<gg, bb, 0, stream>>>(value, Wv, bv, vb, 1.0f);
    attn_mfma_kernel<<<dim3(BATCH * NHEAD * (SEQ / 64)), bb, 0, stream>>>(qb, kb, vb, ctx);
    gemm_bias_kernel<0><<<gg, bb, 0, stream>>>(ctx, Wo, bo, out, 1.0f);
}

// Round 4
// 229.683 us; speedup vs baseline: 4.6248x; 2.6503x over previous
//
#include <hip/hip_runtime.h>
#include <hip/hip_bf16.h>
#include <math.h>

#define BATCH 2
#define SEQ 2048
#define DMODEL 1024
#define NHEAD 16
#define DHEAD 64
#define MTOT (BATCH*SEQ)   // 4096

typedef __attribute__((ext_vector_type(8))) short bf16x8;
typedef __attribute__((ext_vector_type(4))) float f32x4;

static __device__ inline short f2bs(float x) {
    __hip_bfloat16 b = __float2bfloat16(x);
    return *reinterpret_cast<short*>(&b);
}

// ------------------------------------------------------------------
// Batched fp32 -> bf16 conversion over 7 tensors (3x QKV inputs, 4x W).
// Each block converts 2048 elems (256 thr x 8).
// ------------------------------------------------------------------
struct ConvArgs {
    const float* src[7];
    unsigned short* dst[7];
    int nblk[7];
};

__global__ __launch_bounds__(256)
void convert_bf16_kernel(ConvArgs a)
{
    int b = blockIdx.x;
    int r = 0;
    while (b >= a.nblk[r]) { b -= a.nblk[r]; ++r; }
    const float* s = a.src[r];
    unsigned short* d = a.dst[r];
    const int base = b * 2048 + threadIdx.x * 8;
    const float4 f0 = *reinterpret_cast<const float4*>(&s[base]);
    const float4 f1 = *reinterpret_cast<const float4*>(&s[base + 4]);
    bf16x8 o;
    o[0] = f2bs(f0.x); o[1] = f2bs(f0.y); o[2] = f2bs(f0.z); o[3] = f2bs(f0.w);
    o[4] = f2bs(f1.x); o[5] = f2bs(f1.y); o[6] = f2bs(f1.z); o[7] = f2bs(f1.w);
    *reinterpret_cast<bf16x8*>(&d[base]) = o;
}

// ------------------------------------------------------------------
// MFMA bf16 GEMM: out = X[M,1024] @ W[1024,1024]^T + bias (torch Linear).
// X, W bf16 row-major (both K-major). 128x128 tile, BK=64, 4 waves,
// each wave 64x64 via 4x4 frags of mfma_f32_16x16x32_bf16.
// Double-buffered LDS, XOR-swizzled rows (T2), reg-staged prefetch (T14-lite).
// SPLIT=1: write bf16 * scale scattered to [B,H,S,DK].
// SPLIT=0: write fp32 [M,N].
// ------------------------------------------------------------------
template<int SPLIT>
__global__ __launch_bounds__(256)
void gemm_mfma_kernel(const __hip_bfloat16* __restrict__ X,
                      const __hip_bfloat16* __restrict__ W,
                      const float* __restrict__ bias,
                      void* __restrict__ outp, float scale)
{
    __shared__ short Xs[2][128 * 64];   // [row][k], 128B rows, swizzled
    __shared__ short Wt[2][128 * 64];

    const int t    = threadIdx.x;
    const int lane = t & 63;
    const int w    = t >> 6;
    const int wm   = w >> 1, wn = w & 1;
    const int m_   = lane & 15, g = lane >> 4;

    const int m0 = blockIdx.y * 128;
    const int n0 = blockIdx.x * 128;

    const int sr  = t >> 1;            // staging row 0..127
    const int sc0 = (t & 1) * 4;       // 16B-chunk base: 0 or 4

    const short* Xg = (const short*)X;
    const short* Wg = (const short*)W;

    f32x4 acc[4][4] = {};
    bf16x8 xr[4], wr[4];

    // prologue: stage K-tile 0
    #pragma unroll
    for (int c = 0; c < 4; ++c) {
        xr[c] = *reinterpret_cast<const bf16x8*>(&Xg[(size_t)(m0 + sr) * DMODEL + (sc0 + c) * 8]);
        wr[c] = *reinterpret_cast<const bf16x8*>(&Wg[(size_t)(n0 + sr) * DMODEL + (sc0 + c) * 8]);
    }
    #pragma unroll
    for (int c = 0; c < 4; ++c) {
        const int byo = sr * 128 + (((sc0 + c) * 16) ^ ((sr & 7) << 4));
        *reinterpret_cast<bf16x8*>((char*)Xs[0] + byo) = xr[c];
        *reinterpret_cast<bf16x8*>((char*)Wt[0] + byo) = wr[c];
    }
    __syncthreads();

    for (int kt = 0; kt < DMODEL / 64; ++kt) {
        const int cur = kt & 1;
        const bool more = (kt < DMODEL / 64 - 1);

        // issue next tile's global loads early (latency hides under MFMA)
        if (more) {
            const int k0 = (kt + 1) * 64;
            #pragma unroll
            for (int c = 0; c < 4; ++c) {
                xr[c] = *reinterpret_cast<const bf16x8*>(&Xg[(size_t)(m0 + sr) * DMODEL + k0 + (sc0 + c) * 8]);
                wr[c] = *reinterpret_cast<const bf16x8*>(&Wg[(size_t)(n0 + sr) * DMODEL + k0 + (sc0 + c) * 8]);
            }
        }

        // fragments from current buffer
        bf16x8 af[4][2], bfr[4][2];
        #pragma unroll
        for (int mt = 0; mt < 4; ++mt) {
            const int row = wm * 64 + mt * 16 + m_;
            #pragma unroll
            for (int kc = 0; kc < 2; ++kc)
                af[mt][kc] = *reinterpret_cast<const bf16x8*>(
                    (char*)Xs[cur] + row * 128 + ((kc * 64 + g * 16) ^ ((row & 7) << 4)));
        }
        #pragma unroll
        for (int nt = 0; nt < 4; ++nt) {
            const int row = wn * 64 + nt * 16 + m_;
            #pragma unroll
            for (int kc = 0; kc < 2; ++kc)
                bfr[nt][kc] = *reinterpret_cast<const bf16x8*>(
                    (char*)Wt[cur] + row * 128 + ((kc * 64 + g * 16) ^ ((row & 7) << 4)));
        }

        #pragma unroll
        for (int mt = 0; mt < 4; ++mt)
            #pragma unroll
            for (int nt = 0; nt < 4; ++nt)
                #pragma unroll
                for (int kc = 0; kc < 2; ++kc)
                    acc[mt][nt] = __builtin_amdgcn_mfma_f32_16x16x32_bf16(
                        af[mt][kc], bfr[nt][kc], acc[mt][nt], 0, 0, 0);

        if (more) {
            #pragma unroll
            for (int c = 0; c < 4; ++c) {
                const int byo = sr * 128 + (((sc0 + c) * 16) ^ ((sr & 7) << 4));
                *reinterpret_cast<bf16x8*>((char*)Xs[cur ^ 1] + byo) = xr[c];
                *reinterpret_cast<bf16x8*>((char*)Wt[cur ^ 1] + byo) = wr[c];
            }
        }
        __syncthreads();
    }

    // epilogue: bias + scale; C/D layout row=g*4+reg, col=m_
    float bv[4];
    #pragma unroll
    for (int nt = 0; nt < 4; ++nt) bv[nt] = bias[n0 + wn * 64 + nt * 16 + m_];

    #pragma unroll
    for (int mt = 0; mt < 4; ++mt) {
        #pragma unroll
        for (int r = 0; r < 4; ++r) {
            const int row = m0 + wm * 64 + mt * 16 + g * 4 + r;
            const int b = row >> 11;
            const int s = row & 2047;
            #pragma unroll
            for (int nt = 0; nt < 4; ++nt) {
                const int n = n0 + wn * 64 + nt * 16 + m_;
                const float c = (acc[mt][nt][r] + bv[nt]) * scale;
                if (SPLIT) {
                    const int h = n >> 6, dk = n & 63;
                    ((__hip_bfloat16*)outp)[(((size_t)(b * NHEAD + h)) * SEQ + s) * DHEAD + dk]
                        = __float2bfloat16(c);
                } else {
                    ((float*)outp)[(size_t)row * DMODEL + n] = c;
                }
            }
        }
    }
}

// ------------------------------------------------------------------
// MFMA bf16 causal flash attention (validated round 2).
// Block: 4 waves; 64 q-rows/block; KV tile 64. ctx now bf16 [B,S,D].
// ------------------------------------------------------------------
__global__ __launch_bounds__(256)
void attn_mfma_kernel(const __hip_bfloat16* __restrict__ Q,
                      const __hip_bfloat16* __restrict__ K,
                      const __hip_bfloat16* __restrict__ V,
                      __hip_bfloat16* __restrict__ ctx)
{
    __shared__ short Ks[64 * 64];
    __shared__ short Vts[64 * 64];
    __shared__ short Ps[4 * 16 * 72];

    const int t    = threadIdx.x;
    const int lane = t & 63;
    const int w    = t >> 6;
    const int m    = lane & 15;
    const int g    = lane >> 4;

    const int bh = blockIdx.x >> 5;
    const int qt = blockIdx.x & 31;
    const int q0 = qt * 64;

    const __hip_bfloat16* Qb = Q + (size_t)bh * SEQ * DHEAD;
    const __hip_bfloat16* Kb = K + (size_t)bh * SEQ * DHEAD;
    const __hip_bfloat16* Vb = V + (size_t)bh * SEQ * DHEAD;

    bf16x8 qfrag[2];
    #pragma unroll
    for (int c = 0; c < 2; ++c)
        qfrag[c] = *reinterpret_cast<const bf16x8*>(
            &Qb[(size_t)(q0 + 16 * w + m) * DHEAD + c * 32 + 8 * g]);

    f32x4 o[4] = {};
    float mrow[4], lrow[4];
    #pragma unroll
    for (int r = 0; r < 4; ++r) { mrow[r] = -INFINITY; lrow[r] = 0.0f; }

    short* Pw = Ps + w * 16 * 72;

    for (int kt = 0; kt <= qt; ++kt) {
        const int k0 = kt * 64;

        {
            const int row = t >> 2;
            #pragma unroll
            for (int cc = 0; cc < 2; ++cc) {
                const int ch = (t & 3) + cc * 4;
                const bf16x8 kv = *reinterpret_cast<const bf16x8*>(
                    &Kb[(size_t)(k0 + row) * DHEAD + ch * 8]);
                *reinterpret_cast<bf16x8*>((char*)Ks +
                    (((row * 128) + ch * 16) ^ ((row & 7) << 4))) = kv;
            }
            const int vk = t & 63;
            #pragma unroll
            for (int it = 0; it < 2; ++it) {
                const int d0 = (t >> 6) * 16 + it * 8;
                const bf16x8 vv = *reinterpret_cast<const bf16x8*>(
                    &Vb[(size_t)(k0 + vk) * DHEAD + d0]);
                #pragma unroll
                for (int j = 0; j < 8; ++j) {
                    const int d = d0 + j;
                    *reinterpret_cast<short*>((char*)Vts +
                        (((d * 128) + vk * 2) ^ ((d & 7) << 4))) = vv[j];
                }
            }
        }
        __syncthreads();

        f32x4 s[4] = {};
        #pragma unroll
        for (int ct = 0; ct < 4; ++ct) {
            const int krow = ct * 16 + m;
            #pragma unroll
            for (int c = 0; c < 2; ++c) {
                const bf16x8 kf = *reinterpret_cast<const bf16x8*>((char*)Ks +
                    (((krow * 128) + c * 64 + 16 * g) ^ ((krow & 7) << 4)));
                s[ct] = __builtin_amdgcn_mfma_f32_16x16x32_bf16(
                    qfrag[c], kf, s[ct], 0, 0, 0);
            }
        }

        if (kt == qt) {
            #pragma unroll
            for (int ct = 0; ct < 4; ++ct) {
                const int kp = ct * 16 + m;
                #pragma unroll
                for (int r = 0; r < 4; ++r) {
                    const int qr = 16 * w + 4 * g + r;
                    if (kp > qr) s[ct][r] = -INFINITY;
                }
            }
        }

        float pmax[4];
        #pragma unroll
        for (int r = 0; r < 4; ++r)
            pmax[r] = fmaxf(fmaxf(s[0][r], s[1][r]), fmaxf(s[2][r], s[3][r]));
        #pragma unroll
        for (int mk = 1; mk <= 8; mk <<= 1)
            #pragma unroll
            for (int r = 0; r < 4; ++r)
                pmax[r] = fmaxf(pmax[r], __shfl_xor(pmax[r], mk, 64));

        float scl[4];
        #pragma unroll
        for (int r = 0; r < 4; ++r) {
            const float mnew = fmaxf(mrow[r], pmax[r]);
            scl[r]  = __expf(mrow[r] - mnew);
            mrow[r] = mnew;
        }
        #pragma unroll
        for (int ct = 0; ct < 4; ++ct)
            #pragma unroll
            for (int r = 0; r < 4; ++r)
                s[ct][r] = __expf(s[ct][r] - mrow[r]);

        float psum[4];
        #pragma unroll
        for (int r = 0; r < 4; ++r)
            psum[r] = (s[0][r] + s[1][r]) + (s[2][r] + s[3][r]);
        #pragma unroll
        for (int mk = 1; mk <= 8; mk <<= 1)
            #pragma unroll
            for (int r = 0; r < 4; ++r)
                psum[r] += __shfl_xor(psum[r], mk, 64);
        #pragma unroll
        for (int r = 0; r < 4; ++r)
            lrow[r] = lrow[r] * scl[r] + psum[r];

        #pragma unroll
        for (int dt = 0; dt < 4; ++dt)
            #pragma unroll
            for (int r = 0; r < 4; ++r)
                o[dt][r] *= scl[r];

        #pragma unroll
        for (int ct = 0; ct < 4; ++ct)
            #pragma unroll
            for (int r = 0; r < 4; ++r)
                Pw[(4 * g + r) * 72 + ct * 16 + m] = f2bs(s[ct][r]);

        bf16x8 pf[2];
        #pragma unroll
        for (int c = 0; c < 2; ++c)
            pf[c] = *reinterpret_cast<const bf16x8*>(&Pw[m * 72 + c * 32 + 8 * g]);
        #pragma unroll
        for (int dt = 0; dt < 4; ++dt) {
            const int vrow = dt * 16 + m;
            #pragma unroll
            for (int c = 0; c < 2; ++c) {
                const bf16x8 vf = *reinterpret_cast<const bf16x8*>((char*)Vts +
                    (((vrow * 128) + c * 64 + 16 * g) ^ ((vrow & 7) << 4)));
                o[dt] = __builtin_amdgcn_mfma_f32_16x16x32_bf16(
                    pf[c], vf, o[dt], 0, 0, 0);
            }
        }
        __syncthreads();
    }

    const int b = bh >> 4;
    const int h = bh & 15;
    #pragma unroll
    for (int r = 0; r < 4; ++r) {
        const float inv = 1.0f / lrow[r];
        const int qrow = q0 + 16 * w + 4 * g + r;
        __hip_bfloat16* dst = &ctx[((size_t)(b * SEQ) + qrow) * DMODEL + h * DHEAD];
        #pragma unroll
        for (int dt = 0; dt < 4; ++dt)
            dst[dt * 16 + m] = __float2bfloat16(o[dt][r] * inv);
    }
}

// ------------------------------------------------------------------
extern "C" void kernel_launch(void* const* d_in, const int* in_sizes, int n_in,
                              void* d_out, int out_size, void* d_ws, size_t ws_size,
                              hipStream_t stream)
{
    const float* query = (const float*)d_in[0];
    const float* key   = (const float*)d_in[1];
    const float* value = (const float*)d_in[2];
    // d_in[3] = mask: fixed causal tril — implemented directly
    const float* Wq = (const float*)d_in[4];
    const float* bq = (const float*)d_in[5];
    const float* Wk = (const float*)d_in[6];
    const float* bk = (const float*)d_in[7];
    const float* Wv = (const float*)d_in[8];
    const float* bv = (const float*)d_in[9];
    const float* Wo = (const float*)d_in[10];
    const float* bo = (const float*)d_in[11];
    float* out = (float*)d_out;

    // ws layout (bytes):
    //  xq 0..8M, xk 8..16M, xv 16..24M        (bf16 inputs)
    //  wqb 24..26M, wkb 26..28M, wvb 28..30M, wob 30..32M (bf16 weights)
    //  qb 32..40M, kb 40..48M, vb 48..56M     (bf16 projections, [B,H,S,DK])
    //  ctx 56..64M                            (bf16 attention out, [B,S,D])
    char* ws = (char*)d_ws;
    const size_t MB = 1024 * 1024;
    unsigned short* xq  = (unsigned short*)(ws + 0 * MB);
    unsigned short* xk  = (unsigned short*)(ws + 8 * MB);
    unsigned short* xv  = (unsigned short*)(ws + 16 * MB);
    unsigned short* wqb = (unsigned short*)(ws + 24 * MB);
    unsigned short* wkb = (unsigned short*)(ws + 26 * MB);
    unsigned short* wvb = (unsigned short*)(ws + 28 * MB);
    unsigned short* wob = (unsigned short*)(ws + 30 * MB);
    __hip_bfloat16* qb  = (__hip_bfloat16*)(ws + 32 * MB);
    __hip_bfloat16* kb  = (__hip_bfloat16*)(ws + 40 * MB);
    __hip_bfloat16* vb  = (__hip_bfloat16*)(ws + 48 * MB);
    __hip_bfloat16* ctx = (__hip_bfloat16*)(ws + 56 * MB);

    ConvArgs ca;
    ca.src[0] = query; ca.dst[0] = xq;  ca.nblk[0] = 2048;
    ca.src[1] = key;   ca.dst[1] = xk;  ca.nblk[1] = 2048;
    ca.src[2] = value; ca.dst[2] = xv;  ca.nblk[2] = 2048;
    ca.src[3] = Wq;    ca.dst[3] = wqb; ca.nblk[3] = 512;
    ca.src[4] = Wk;    ca.dst[4] = wkb; ca.nblk[4] = 512;
    ca.src[5] = Wv;    ca.dst[5] = wvb; ca.nblk[5] = 512;
    ca.src[6] = Wo;    ca.dst[6] = wob; ca.nblk[6] = 512;
    convert_bf16_kernel<<<dim3(8192), dim3(256), 0, stream>>>(ca);

    const dim3 gg(DMODEL / 128, MTOT / 128);   // (8, 32)
    const dim3 bb(256);
    gemm_mfma_kernel<1><<<gg, bb, 0, stream>>>(
        (const __hip_bfloat16*)xq, (const __hip_bfloat16*)wqb, bq, qb, 0.125f);
    gemm_mfma_kernel<1><<<gg, bb, 0, stream>>>(
        (const __hip_bfloat16*)xk, (const __hip_bfloat16*)wkb, bk, kb, 1.0f);
    gemm_mfma_kernel<1><<<gg, bb, 0, stream>>>(
        (const __hip_bfloat16*)xv, (const __hip_bfloat16*)wvb, bv, vb, 1.0f);
    attn_mfma_kernel<<<dim3(BATCH * NHEAD * (SEQ / 64)), bb, 0, stream>>>(qb, kb, vb, ctx);
    gemm_mfma_kernel<0><<<gg, bb, 0, stream>>>(
        (const __hip_bfloat16*)ctx, (const __hip_bfloat16*)wob, bo, out, 1.0f);
}

// Round 5
// 186.190 us; speedup vs baseline: 5.7052x; 1.2336x over previous
//
#include <hip/hip_runtime.h>
#include <hip/hip_bf16.h>
#include <math.h>

#define BATCH 2
#define SEQ 2048
#define DMODEL 1024
#define NHEAD 16
#define DHEAD 64
#define MTOT (BATCH*SEQ)   // 4096

typedef __attribute__((ext_vector_type(8))) short bf16x8;
typedef __attribute__((ext_vector_type(4))) float f32x4;

static __device__ inline short f2bs(float x) {
    __hip_bfloat16 b = __float2bfloat16(x);
    return *reinterpret_cast<short*>(&b);
}

// ------------------------------------------------------------------
// Batched fp32 -> bf16 conversion over 7 tensors.
// ------------------------------------------------------------------
struct ConvArgs {
    const float* src[7];
    unsigned short* dst[7];
    int nblk[7];
};

__global__ __launch_bounds__(256)
void convert_bf16_kernel(ConvArgs a)
{
    int b = blockIdx.x;
    int r = 0;
    while (b >= a.nblk[r]) { b -= a.nblk[r]; ++r; }
    const float* s = a.src[r];
    unsigned short* d = a.dst[r];
    const int base = b * 2048 + threadIdx.x * 8;
    const float4 f0 = *reinterpret_cast<const float4*>(&s[base]);
    const float4 f1 = *reinterpret_cast<const float4*>(&s[base + 4]);
    bf16x8 o;
    o[0] = f2bs(f0.x); o[1] = f2bs(f0.y); o[2] = f2bs(f0.z); o[3] = f2bs(f0.w);
    o[4] = f2bs(f1.x); o[5] = f2bs(f1.y); o[6] = f2bs(f1.z); o[7] = f2bs(f1.w);
    *reinterpret_cast<bf16x8*>(&d[base]) = o;
}

// ------------------------------------------------------------------
// MFMA bf16 GEMM (validated round 3): out = X @ W^T + bias.
// 128x128 tile, BK=64, double-buffered swizzled LDS, reg-staged prefetch.
// ------------------------------------------------------------------
template<int SPLIT>
__global__ __launch_bounds__(256)
void gemm_mfma_kernel(const __hip_bfloat16* __restrict__ X,
                      const __hip_bfloat16* __restrict__ W,
                      const float* __restrict__ bias,
                      void* __restrict__ outp, float scale)
{
    __shared__ short Xs[2][128 * 64];
    __shared__ short Wt[2][128 * 64];

    const int t    = threadIdx.x;
    const int lane = t & 63;
    const int w    = t >> 6;
    const int wm   = w >> 1, wn = w & 1;
    const int m_   = lane & 15, g = lane >> 4;

    const int m0 = blockIdx.y * 128;
    const int n0 = blockIdx.x * 128;

    const int sr  = t >> 1;
    const int sc0 = (t & 1) * 4;

    const short* Xg = (const short*)X;
    const short* Wg = (const short*)W;

    f32x4 acc[4][4] = {};
    bf16x8 xr[4], wr[4];

    #pragma unroll
    for (int c = 0; c < 4; ++c) {
        xr[c] = *reinterpret_cast<const bf16x8*>(&Xg[(size_t)(m0 + sr) * DMODEL + (sc0 + c) * 8]);
        wr[c] = *reinterpret_cast<const bf16x8*>(&Wg[(size_t)(n0 + sr) * DMODEL + (sc0 + c) * 8]);
    }
    #pragma unroll
    for (int c = 0; c < 4; ++c) {
        const int byo = sr * 128 + (((sc0 + c) * 16) ^ ((sr & 7) << 4));
        *reinterpret_cast<bf16x8*>((char*)Xs[0] + byo) = xr[c];
        *reinterpret_cast<bf16x8*>((char*)Wt[0] + byo) = wr[c];
    }
    __syncthreads();

    for (int kt = 0; kt < DMODEL / 64; ++kt) {
        const int cur = kt & 1;
        const bool more = (kt < DMODEL / 64 - 1);

        if (more) {
            const int k0 = (kt + 1) * 64;
            #pragma unroll
            for (int c = 0; c < 4; ++c) {
                xr[c] = *reinterpret_cast<const bf16x8*>(&Xg[(size_t)(m0 + sr) * DMODEL + k0 + (sc0 + c) * 8]);
                wr[c] = *reinterpret_cast<const bf16x8*>(&Wg[(size_t)(n0 + sr) * DMODEL + k0 + (sc0 + c) * 8]);
            }
        }

        bf16x8 af[4][2], bfr[4][2];
        #pragma unroll
        for (int mt = 0; mt < 4; ++mt) {
            const int row = wm * 64 + mt * 16 + m_;
            #pragma unroll
            for (int kc = 0; kc < 2; ++kc)
                af[mt][kc] = *reinterpret_cast<const bf16x8*>(
                    (char*)Xs[cur] + row * 128 + ((kc * 64 + g * 16) ^ ((row & 7) << 4)));
        }
        #pragma unroll
        for (int nt = 0; nt < 4; ++nt) {
            const int row = wn * 64 + nt * 16 + m_;
            #pragma unroll
            for (int kc = 0; kc < 2; ++kc)
                bfr[nt][kc] = *reinterpret_cast<const bf16x8*>(
                    (char*)Wt[cur] + row * 128 + ((kc * 64 + g * 16) ^ ((row & 7) << 4)));
        }

        __builtin_amdgcn_s_setprio(1);
        #pragma unroll
        for (int mt = 0; mt < 4; ++mt)
            #pragma unroll
            for (int nt = 0; nt < 4; ++nt)
                #pragma unroll
                for (int kc = 0; kc < 2; ++kc)
                    acc[mt][nt] = __builtin_amdgcn_mfma_f32_16x16x32_bf16(
                        af[mt][kc], bfr[nt][kc], acc[mt][nt], 0, 0, 0);
        __builtin_amdgcn_s_setprio(0);

        if (more) {
            #pragma unroll
            for (int c = 0; c < 4; ++c) {
                const int byo = sr * 128 + (((sc0 + c) * 16) ^ ((sr & 7) << 4));
                *reinterpret_cast<bf16x8*>((char*)Xs[cur ^ 1] + byo) = xr[c];
                *reinterpret_cast<bf16x8*>((char*)Wt[cur ^ 1] + byo) = wr[c];
            }
        }
        __syncthreads();
    }

    float bv[4];
    #pragma unroll
    for (int nt = 0; nt < 4; ++nt) bv[nt] = bias[n0 + wn * 64 + nt * 16 + m_];

    #pragma unroll
    for (int mt = 0; mt < 4; ++mt) {
        #pragma unroll
        for (int r = 0; r < 4; ++r) {
            const int row = m0 + wm * 64 + mt * 16 + g * 4 + r;
            const int b = row >> 11;
            const int s = row & 2047;
            #pragma unroll
            for (int nt = 0; nt < 4; ++nt) {
                const int n = n0 + wn * 64 + nt * 16 + m_;
                const float c = (acc[mt][nt][r] + bv[nt]) * scale;
                if (SPLIT) {
                    const int h = n >> 6, dk = n & 63;
                    ((__hip_bfloat16*)outp)[(((size_t)(b * NHEAD + h)) * SEQ + s) * DHEAD + dk]
                        = __float2bfloat16(c);
                } else {
                    ((float*)outp)[(size_t)row * DMODEL + n] = c;
                }
            }
        }
    }
}

// ------------------------------------------------------------------
// Online-softmax helper: s[4] (4 col-tiles x 4 rows) -> P in s, updates m/l,
// rescales O. Reduction across the 16 m-lanes (xor 1,2,4,8).
// ------------------------------------------------------------------
static __device__ inline void online_sm(f32x4 s[4], float mrow[4], float lrow[4],
                                        f32x4 o[4])
{
    float pmax[4];
    #pragma unroll
    for (int r = 0; r < 4; ++r)
        pmax[r] = fmaxf(fmaxf(s[0][r], s[1][r]), fmaxf(s[2][r], s[3][r]));
    #pragma unroll
    for (int mk = 1; mk <= 8; mk <<= 1)
        #pragma unroll
        for (int r = 0; r < 4; ++r)
            pmax[r] = fmaxf(pmax[r], __shfl_xor(pmax[r], mk, 64));

    float scl[4];
    #pragma unroll
    for (int r = 0; r < 4; ++r) {
        const float mnew = fmaxf(mrow[r], pmax[r]);
        scl[r]  = __expf(mrow[r] - mnew);
        mrow[r] = mnew;
    }
    #pragma unroll
    for (int ct = 0; ct < 4; ++ct)
        #pragma unroll
        for (int r = 0; r < 4; ++r)
            s[ct][r] = __expf(s[ct][r] - mrow[r]);

    float psum[4];
    #pragma unroll
    for (int r = 0; r < 4; ++r)
        psum[r] = (s[0][r] + s[1][r]) + (s[2][r] + s[3][r]);
    #pragma unroll
    for (int mk = 1; mk <= 8; mk <<= 1)
        #pragma unroll
        for (int r = 0; r < 4; ++r)
            psum[r] += __shfl_xor(psum[r], mk, 64);
    #pragma unroll
    for (int r = 0; r < 4; ++r)
        lrow[r] = lrow[r] * scl[r] + psum[r];

    #pragma unroll
    for (int dt = 0; dt < 4; ++dt)
        #pragma unroll
        for (int r = 0; r < 4; ++r)
            o[dt][r] *= scl[r];
}

// ------------------------------------------------------------------
// Paired-tile MFMA causal flash attention.
// Block = (b,h, pair pr): q-tiles qtA=pr, qtB=31-pr -> constant 33 tile-units.
// 4 waves, each owns 16 q-rows of BOTH tiles. K/V staged once per kt, shared.
// ------------------------------------------------------------------
__global__ __launch_bounds__(256)
void attn_mfma_kernel(const __hip_bfloat16* __restrict__ Q,
                      const __hip_bfloat16* __restrict__ K,
                      const __hip_bfloat16* __restrict__ V,
                      __hip_bfloat16* __restrict__ ctx)
{
    __shared__ short Ks[64 * 64];          // K tile [kv][d], swizzled 128B rows
    __shared__ short Vts[64 * 64];         // V^T tile [d][kv], swizzled
    __shared__ short Ps[4 * 2 * 16 * 72];  // per-wave, per-side P tiles

    const int t    = threadIdx.x;
    const int lane = t & 63;
    const int w    = t >> 6;
    const int m    = lane & 15;
    const int g    = lane >> 4;

    // XCD-chunked swizzle: grid 512 = 8 XCDs x 64; XCD x gets work [x*64,(x+1)*64)
    const int bid = blockIdx.x;
    const int swz = (bid & 7) * 64 + (bid >> 3);
    const int bh  = swz >> 4;        // 0..31
    const int pr  = swz & 15;        // 0..15
    const int qtA = pr, qtB = 31 - pr;
    const int q0A = qtA * 64, q0B = qtB * 64;

    const __hip_bfloat16* Qb = Q + (size_t)bh * SEQ * DHEAD;
    const __hip_bfloat16* Kb = K + (size_t)bh * SEQ * DHEAD;
    const __hip_bfloat16* Vb = V + (size_t)bh * SEQ * DHEAD;

    bf16x8 qfA[2], qfB[2];
    #pragma unroll
    for (int c = 0; c < 2; ++c) {
        qfA[c] = *reinterpret_cast<const bf16x8*>(
            &Qb[(size_t)(q0A + 16 * w + m) * DHEAD + c * 32 + 8 * g]);
        qfB[c] = *reinterpret_cast<const bf16x8*>(
            &Qb[(size_t)(q0B + 16 * w + m) * DHEAD + c * 32 + 8 * g]);
    }

    f32x4 oA[4] = {}, oB[4] = {};
    float mA[4], lA[4], mB[4], lB[4];
    #pragma unroll
    for (int r = 0; r < 4; ++r) {
        mA[r] = -INFINITY; lA[r] = 0.0f;
        mB[r] = -INFINITY; lB[r] = 0.0f;
    }

    short* PwA = Ps + (w * 2 + 0) * 16 * 72;
    short* PwB = Ps + (w * 2 + 1) * 16 * 72;

    for (int kt = 0; kt <= qtB; ++kt) {
        const int k0 = kt * 64;
        const bool actA = (kt <= qtA);

        // ---- stage K tile + V^T tile (shared by both q-tiles) ----
        {
            const int row = t >> 2;
            #pragma unroll
            for (int cc = 0; cc < 2; ++cc) {
                const int ch = (t & 3) + cc * 4;
                const bf16x8 kv = *reinterpret_cast<const bf16x8*>(
                    &Kb[(size_t)(k0 + row) * DHEAD + ch * 8]);
                *reinterpret_cast<bf16x8*>((char*)Ks +
                    (((row * 128) + ch * 16) ^ ((row & 7) << 4))) = kv;
            }
            const int vk = t & 63;
            #pragma unroll
            for (int it = 0; it < 2; ++it) {
                const int d0 = w * 16 + it * 8;
                const bf16x8 vv = *reinterpret_cast<const bf16x8*>(
                    &Vb[(size_t)(k0 + vk) * DHEAD + d0]);
                #pragma unroll
                for (int j = 0; j < 8; ++j) {
                    const int d = d0 + j;
                    *reinterpret_cast<short*>((char*)Vts +
                        (((d * 128) + vk * 2) ^ ((d & 7) << 4))) = vv[j];
                }
            }
        }
        __syncthreads();

        // ---- QK^T for both sides (K fragments shared) ----
        f32x4 sA[4] = {}, sB[4] = {};
        __builtin_amdgcn_s_setprio(1);
        #pragma unroll
        for (int ct = 0; ct < 4; ++ct) {
            const int krow = ct * 16 + m;
            #pragma unroll
            for (int c = 0; c < 2; ++c) {
                const bf16x8 kf = *reinterpret_cast<const bf16x8*>((char*)Ks +
                    (((krow * 128) + c * 64 + 16 * g) ^ ((krow & 7) << 4)));
                sB[ct] = __builtin_amdgcn_mfma_f32_16x16x32_bf16(qfB[c], kf, sB[ct], 0, 0, 0);
                if (actA)
                    sA[ct] = __builtin_amdgcn_mfma_f32_16x16x32_bf16(qfA[c], kf, sA[ct], 0, 0, 0);
            }
        }
        __builtin_amdgcn_s_setprio(0);

        // ---- causal masks on diagonal tiles ----
        if (kt == qtA) {
            #pragma unroll
            for (int ct = 0; ct < 4; ++ct) {
                const int kp = ct * 16 + m;
                #pragma unroll
                for (int r = 0; r < 4; ++r)
                    if (kp > 16 * w + 4 * g + r) sA[ct][r] = -INFINITY;
            }
        }
        if (kt == qtB) {
            #pragma unroll
            for (int ct = 0; ct < 4; ++ct) {
                const int kp = ct * 16 + m;
                #pragma unroll
                for (int r = 0; r < 4; ++r)
                    if (kp > 16 * w + 4 * g + r) sB[ct][r] = -INFINITY;
            }
        }

        // ---- online softmax (two independent chains -> ILP) ----
        if (actA) online_sm(sA, mA, lA, oA);
        online_sm(sB, mB, lB, oB);

        // ---- write P tiles (bf16) ----
        if (actA) {
            #pragma unroll
            for (int ct = 0; ct < 4; ++ct)
                #pragma unroll
                for (int r = 0; r < 4; ++r)
                    PwA[(4 * g + r) * 72 + ct * 16 + m] = f2bs(sA[ct][r]);
        }
        #pragma unroll
        for (int ct = 0; ct < 4; ++ct)
            #pragma unroll
            for (int r = 0; r < 4; ++r)
                PwB[(4 * g + r) * 72 + ct * 16 + m] = f2bs(sB[ct][r]);

        bf16x8 pfA[2], pfB[2];
        #pragma unroll
        for (int c = 0; c < 2; ++c) {
            if (actA)
                pfA[c] = *reinterpret_cast<const bf16x8*>(&PwA[m * 72 + c * 32 + 8 * g]);
            pfB[c] = *reinterpret_cast<const bf16x8*>(&PwB[m * 72 + c * 32 + 8 * g]);
        }

        // ---- PV for both sides (V fragments shared) ----
        __builtin_amdgcn_s_setprio(1);
        #pragma unroll
        for (int dt = 0; dt < 4; ++dt) {
            const int vrow = dt * 16 + m;
            #pragma unroll
            for (int c = 0; c < 2; ++c) {
                const bf16x8 vf = *reinterpret_cast<const bf16x8*>((char*)Vts +
                    (((vrow * 128) + c * 64 + 16 * g) ^ ((vrow & 7) << 4)));
                oB[dt] = __builtin_amdgcn_mfma_f32_16x16x32_bf16(pfB[c], vf, oB[dt], 0, 0, 0);
                if (actA)
                    oA[dt] = __builtin_amdgcn_mfma_f32_16x16x32_bf16(pfA[c], vf, oA[dt], 0, 0, 0);
            }
        }
        __builtin_amdgcn_s_setprio(0);
        __syncthreads();
    }

    // ---- epilogue: both tiles -> ctx bf16 [B,S,D] ----
    const int b = bh >> 4;
    const int h = bh & 15;
    #pragma unroll
    for (int r = 0; r < 4; ++r) {
        const float invA = 1.0f / lA[r];
        const float invB = 1.0f / lB[r];
        const int rowA = q0A + 16 * w + 4 * g + r;
        const int rowB = q0B + 16 * w + 4 * g + r;
        __hip_bfloat16* dA = &ctx[((size_t)(b * SEQ) + rowA) * DMODEL + h * DHEAD];
        __hip_bfloat16* dB = &ctx[((size_t)(b * SEQ) + rowB) * DMODEL + h * DHEAD];
        #pragma unroll
        for (int dt = 0; dt < 4; ++dt) {
            dA[dt * 16 + m] = __float2bfloat16(oA[dt][r] * invA);
            dB[dt * 16 + m] = __float2bfloat16(oB[dt][r] * invB);
        }
    }
}

// ------------------------------------------------------------------
extern "C" void kernel_launch(void* const* d_in, const int* in_sizes, int n_in,
                              void* d_out, int out_size, void* d_ws, size_t ws_size,
                              hipStream_t stream)
{
    const float* query = (const float*)d_in[0];
    const float* key   = (const float*)d_in[1];
    const float* value = (const float*)d_in[2];
    // d_in[3] = mask: fixed causal tril — implemented directly
    const float* Wq = (const float*)d_in[4];
    const float* bq = (const float*)d_in[5];
    const float* Wk = (const float*)d_in[6];
    const float* bk = (const float*)d_in[7];
    const float* Wv = (const float*)d_in[8];
    const float* bv = (const float*)d_in[9];
    const float* Wo = (const float*)d_in[10];
    const float* bo = (const float*)d_in[11];
    float* out = (float*)d_out;

    char* ws = (char*)d_ws;
    const size_t MB = 1024 * 1024;
    unsigned short* xq  = (unsigned short*)(ws + 0 * MB);
    unsigned short* xk  = (unsigned short*)(ws + 8 * MB);
    unsigned short* xv  = (unsigned short*)(ws + 16 * MB);
    unsigned short* wqb = (unsigned short*)(ws + 24 * MB);
    unsigned short* wkb = (unsigned short*)(ws + 26 * MB);
    unsigned short* wvb = (unsigned short*)(ws + 28 * MB);
    unsigned short* wob = (unsigned short*)(ws + 30 * MB);
    __hip_bfloat16* qb  = (__hip_bfloat16*)(ws + 32 * MB);
    __hip_bfloat16* kb  = (__hip_bfloat16*)(ws + 40 * MB);
    __hip_bfloat16* vb  = (__hip_bfloat16*)(ws + 48 * MB);
    __hip_bfloat16* ctx = (__hip_bfloat16*)(ws + 56 * MB);

    ConvArgs ca;
    ca.src[0] = query; ca.dst[0] = xq;  ca.nblk[0] = 2048;
    ca.src[1] = key;   ca.dst[1] = xk;  ca.nblk[1] = 2048;
    ca.src[2] = value; ca.dst[2] = xv;  ca.nblk[2] = 2048;
    ca.src[3] = Wq;    ca.dst[3] = wqb; ca.nblk[3] = 512;
    ca.src[4] = Wk;    ca.dst[4] = wkb; ca.nblk[4] = 512;
    ca.src[5] = Wv;    ca.dst[5] = wvb; ca.nblk[5] = 512;
    ca.src[6] = Wo;    ca.dst[6] = wob; ca.nblk[6] = 512;
    convert_bf16_kernel<<<dim3(8192), dim3(256), 0, stream>>>(ca);

    const dim3 gg(DMODEL / 128, MTOT / 128);   // (8, 32)
    const dim3 bb(256);
    gemm_mfma_kernel<1><<<gg, bb, 0, stream>>>(
        (const __hip_bfloat16*)xq, (const __hip_bfloat16*)wqb, bq, qb, 0.125f);
    gemm_mfma_kernel<1><<<gg, bb, 0, stream>>>(
        (const __hip_bfloat16*)xk, (const __hip_bfloat16*)wkb, bk, kb, 1.0f);
    gemm_mfma_kernel<1><<<gg, bb, 0, stream>>>(
        (const __hip_bfloat16*)xv, (const __hip_bfloat16*)wvb, bv, vb, 1.0f);
    attn_mfma_kernel<<<dim3(512), bb, 0, stream>>>(qb, kb, vb, ctx);
    gemm_mfma_kernel<0><<<gg, bb, 0, stream>>>(
        (const __hip_bfloat16*)ctx, (const __hip_bfloat16*)wob, bo, out, 1.0f);
}